// Round 6
// baseline (418.407 us; speedup 1.0000x reference)
//
#include <hip/hip_runtime.h>

// GCNConv: out = D^-1/2 (A+I) D^-1/2 X W + b
// N=100000, E=1600000, Din=Dout=128; x/W/b fp32, edge_index int32, out fp32.
//
// R10: direct-to-node atomic placement (sort machinery deleted).
//   1. memset cnt/degf (800KB)
//   2. k_deg   : atomicAdd(&cnt[col],1)  (+ W-prep fold, blocks 0..63)
//   3. k_scan1 : rowptr = excl-prefix(cnt)   (25 blocks over N=100K)
//   4. k_scan2 : block offsets boff (+ rowptr[N] fixup)
//   5. k_pg    : place (atomicSub(&cnt[c],1) -> unique CSR slot, write
//                spack[pos]=(row,w), degf atomicAdd)  +  ALL gemm blocks
//                (block-range split; atomic-latency place overlaps MFMA)
//   6. k_gather: R4 structure (proven 74-75us), dis computed on the fly
//                as rsqrtf(degf+1), jb/je add deferred boff.
// Deleted vs R9: 611K-cell coarse histogram (2 scattered ~39MB passes),
// srw intermediate (25.6MB r+w), k_fine, k_dis.

#define ELEMS_PER_SCAN_BLOCK 4096  // 256 threads * 16
#define SCAN_SHIFT 12
#define CHUNK_D 4096               // edges per deg block
#define CHUNK_P 2048               // edges per place block

typedef __attribute__((ext_vector_type(8))) short short8;
typedef __attribute__((ext_vector_type(4))) float f32x4;

__device__ inline unsigned short f2bf(float f) {  // fp32 -> bf16 RNE
    unsigned u = __float_as_uint(f);
    u += 0x7fffu + ((u >> 16) & 1u);
    return (unsigned short)(u >> 16);
}
__device__ inline float bf_lo(unsigned u) { return __uint_as_float(u << 16); }
__device__ inline float bf_hi(unsigned u) { return __uint_as_float(u & 0xffff0000u); }

// ---- degree count (global atomics) + W-prep fold ----
__global__ __launch_bounds__(256) void k_deg(const int* __restrict__ col,
                                             const float* __restrict__ W,
                                             int* __restrict__ cnt,
                                             unsigned short* __restrict__ Wtg,
                                             int E) {
    int t = threadIdx.x, blk = blockIdx.x;
    if (blk < 64) {  // W transpose+bf16: 2 rows per block
        int n = blk * 2 + (t >> 7);
        int k = t & 127;
        Wtg[n * 128 + k] = f2bf(W[k * 128 + n]);
    }
    int base = blk * CHUNK_D;
    #pragma unroll
    for (int i = 0; i < CHUNK_D / 256; ++i) {
        int e = base + i * 256 + t;
        if (e < E) atomicAdd(&cnt[col[e]], 1);
    }
}

// ---- scan ----
__device__ inline int wave_incl_scan(int x, int lane) {
    #pragma unroll
    for (int d = 1; d < 64; d <<= 1) {
        int y = __shfl_up(x, d, 64);
        if (lane >= d) x += y;
    }
    return x;
}

__global__ void k_scan1(const int* __restrict__ in, int* __restrict__ out,
                        int* __restrict__ bsum, int M) {
    __shared__ int wsum[4];
    __shared__ int woff[4];
    int t = threadIdx.x, lane = t & 63, wid = t >> 6;
    int base = blockIdx.x * ELEMS_PER_SCAN_BLOCK + t * 16;
    int v[16];
    #pragma unroll
    for (int i = 0; i < 16; ++i) v[i] = (base + i < M) ? in[base + i] : 0;
    int run = 0;
    #pragma unroll
    for (int i = 0; i < 16; ++i) { int x = v[i]; v[i] = run; run += x; }
    int incl = wave_incl_scan(run, lane);
    int excl = incl - run;
    if (lane == 63) wsum[wid] = incl;
    __syncthreads();
    if (t == 0) {
        int r = 0;
        #pragma unroll
        for (int w = 0; w < 4; ++w) { int s = wsum[w]; woff[w] = r; r += s; }
        bsum[blockIdx.x] = r;
    }
    __syncthreads();
    int off = woff[wid] + excl;
    #pragma unroll
    for (int i = 0; i < 16; ++i)
        if (base + i < M) out[base + i] = v[i] + off;
}

__global__ void k_scan2(const int* __restrict__ bsum, int* __restrict__ boff,
                        int* __restrict__ rowptr, int N, int E, int NB) {
    __shared__ int wsum[4];
    __shared__ int woff[4];
    int t = threadIdx.x, lane = t & 63, wid = t >> 6;
    int x = (t < NB) ? bsum[t] : 0;
    int incl = wave_incl_scan(x, lane);
    int excl = incl - x;
    if (lane == 63) wsum[wid] = incl;
    __syncthreads();
    if (t == 0) {
        int r = 0;
        #pragma unroll
        for (int w = 0; w < 4; ++w) { int s = wsum[w]; woff[w] = r; r += s; }
    }
    __syncthreads();
    if (t < NB) {
        int b = woff[wid] + excl;
        boff[t] = b;
        // rowptr[N] + boff[N>>12] must equal E
        if (t == (N >> SCAN_SHIFT)) rowptr[N] = E - b;
    }
}

// ---- gemm shared-mem + body (64 rows x 128 cols per block) ----
struct GSmem { short Xs[64][136]; short Ws[128][136]; };

__device__ __forceinline__ void gemm_body(GSmem& sm, const float* __restrict__ x,
                                          const unsigned short* __restrict__ Wtg,
                                          unsigned short* __restrict__ h,
                                          int row0, int N, int t) {
    int lane = t & 63, wid = t >> 6;
    {
        int r = t >> 2;
        int kseg = (t & 3) * 32;
        int gr = row0 + r;
        const float4* src = (const float4*)(x + (size_t)gr * 128 + kseg);
        #pragma unroll
        for (int i = 0; i < 4; ++i) {
            float4 v0 = make_float4(0.f, 0.f, 0.f, 0.f), v1 = v0;
            if (gr < N) { v0 = src[2 * i]; v1 = src[2 * i + 1]; }
            short8 p;
            p[0] = (short)f2bf(v0.x); p[1] = (short)f2bf(v0.y);
            p[2] = (short)f2bf(v0.z); p[3] = (short)f2bf(v0.w);
            p[4] = (short)f2bf(v1.x); p[5] = (short)f2bf(v1.y);
            p[6] = (short)f2bf(v1.z); p[7] = (short)f2bf(v1.w);
            *(short8*)&sm.Xs[r][kseg + 8 * i] = p;
        }
    }
    {
        int n = t >> 1;
        int seg = (t & 1) * 64;
        const short* wsrc = (const short*)Wtg + n * 128 + seg;
        #pragma unroll
        for (int i = 0; i < 8; ++i)
            *(short8*)&sm.Ws[n][seg + 8 * i] = *(const short8*)(wsrc + 8 * i);
    }
    __syncthreads();

    int q = lane >> 4;
    int m = lane & 15;
    f32x4 acc[8];
    #pragma unroll
    for (int tde = 0; tde < 8; ++tde) acc[tde] = (f32x4){0.f, 0.f, 0.f, 0.f};
    #pragma unroll
    for (int kc = 0; kc < 128; kc += 32) {
        short8 af = *(const short8*)&sm.Xs[wid * 16 + m][kc + q * 8];
        #pragma unroll
        for (int tde = 0; tde < 8; ++tde) {
            short8 bf = *(const short8*)&sm.Ws[tde * 16 + m][kc + q * 8];
            acc[tde] = __builtin_amdgcn_mfma_f32_16x16x32_bf16(af, bf, acc[tde], 0, 0, 0);
        }
    }
    #pragma unroll
    for (int r = 0; r < 4; ++r) {
        int grow = row0 + wid * 16 + q * 4 + r;
        if (grow < N) {
            #pragma unroll
            for (int tde = 0; tde < 8; ++tde)
                h[(size_t)grow * 128 + tde * 16 + m] = f2bf(acc[tde][r]);
        }
    }
}

// ---- fused: place (blocks [0,NBLKP)) + gemm (blocks [NBLKP, NBLKP+GB)) ----
__global__ __launch_bounds__(256) void k_pg(const int* __restrict__ row,
                                            const int* __restrict__ col,
                                            const float* __restrict__ wgt,
                                            const int* __restrict__ rowptr,
                                            const int* __restrict__ boff,
                                            int* __restrict__ cnt,
                                            float* __restrict__ degf,
                                            int2* __restrict__ spack,
                                            const float* __restrict__ x,
                                            const unsigned short* __restrict__ Wtg,
                                            unsigned short* __restrict__ h,
                                            int E, int N, int NBLKP) {
    __shared__ GSmem sm;
    int t = threadIdx.x;
    if ((int)blockIdx.x >= NBLKP) {  // gemm branch
        gemm_body(sm, x, Wtg, h, ((int)blockIdx.x - NBLKP) * 64, N, t);
        return;
    }
    int base = (int)blockIdx.x * CHUNK_P;
    #pragma unroll
    for (int i = 0; i < CHUNK_P / 256; ++i) {
        int e = base + i * 256 + t;
        if (e < E) {
            int c = col[e];
            float w = wgt[e];
            atomicAdd(&degf[c], w);
            int old = atomicSub(&cnt[c], 1);
            int pos = rowptr[c] + boff[c >> SCAN_SHIFT] + old - 1;
            spack[pos] = make_int2(row[e], __float_as_int(w));
        }
    }
}

// ---- gather: R4 1-wave-per-node, unroll-8 + pipelined spack; dis on the fly ----
__global__ __launch_bounds__(256) void k_gather(const unsigned int* __restrict__ hb,
                                                const float* __restrict__ degf,
                                                const int* __restrict__ rowptr,
                                                const int* __restrict__ boff,
                                                const long* __restrict__ spackl,
                                                const float* __restrict__ bias,
                                                float* __restrict__ out, int N) {
    int gid = blockIdx.x * blockDim.x + threadIdx.x;
    int node = gid >> 6;
    int lane = gid & 63;
    if (node >= N) return;
    node = __builtin_amdgcn_readfirstlane(node);

    float dn = __frsqrt_rn(degf[node] + 1.0f);
    unsigned u = hb[(size_t)node * 64 + lane];
    float2 acc;
    acc.x = dn * bf_lo(u);
    acc.y = dn * bf_hi(u);

    int jb = rowptr[node] + boff[node >> SCAN_SHIFT];
    int je = rowptr[node + 1] + boff[(node + 1) >> SCAN_SHIFT];
    int j = jb;
    long q0, q1, q2, q3, q4, q5, q6, q7;
    if (j + 8 <= je) {
        q0 = __builtin_nontemporal_load(spackl + j);
        q1 = __builtin_nontemporal_load(spackl + j + 1);
        q2 = __builtin_nontemporal_load(spackl + j + 2);
        q3 = __builtin_nontemporal_load(spackl + j + 3);
        q4 = __builtin_nontemporal_load(spackl + j + 4);
        q5 = __builtin_nontemporal_load(spackl + j + 5);
        q6 = __builtin_nontemporal_load(spackl + j + 6);
        q7 = __builtin_nontemporal_load(spackl + j + 7);
    }
    for (; j + 8 <= je; j += 8) {
        int r0 = __builtin_amdgcn_readfirstlane((int)q0);
        int r1 = __builtin_amdgcn_readfirstlane((int)q1);
        int r2 = __builtin_amdgcn_readfirstlane((int)q2);
        int r3 = __builtin_amdgcn_readfirstlane((int)q3);
        int r4 = __builtin_amdgcn_readfirstlane((int)q4);
        int r5 = __builtin_amdgcn_readfirstlane((int)q5);
        int r6 = __builtin_amdgcn_readfirstlane((int)q6);
        int r7 = __builtin_amdgcn_readfirstlane((int)q7);
        unsigned u0 = hb[(size_t)r0 * 64 + lane];
        unsigned u1 = hb[(size_t)r1 * 64 + lane];
        unsigned u2 = hb[(size_t)r2 * 64 + lane];
        unsigned u3 = hb[(size_t)r3 * 64 + lane];
        unsigned u4 = hb[(size_t)r4 * 64 + lane];
        unsigned u5 = hb[(size_t)r5 * 64 + lane];
        unsigned u6 = hb[(size_t)r6 * 64 + lane];
        unsigned u7 = hb[(size_t)r7 * 64 + lane];
        int jn = (j + 16 <= je) ? j + 8 : j;
        long n0 = __builtin_nontemporal_load(spackl + jn);
        long n1 = __builtin_nontemporal_load(spackl + jn + 1);
        long n2 = __builtin_nontemporal_load(spackl + jn + 2);
        long n3 = __builtin_nontemporal_load(spackl + jn + 3);
        long n4 = __builtin_nontemporal_load(spackl + jn + 4);
        long n5 = __builtin_nontemporal_load(spackl + jn + 5);
        long n6 = __builtin_nontemporal_load(spackl + jn + 6);
        long n7 = __builtin_nontemporal_load(spackl + jn + 7);
        float a0 = __frsqrt_rn(degf[r0] + 1.0f) * __uint_as_float((unsigned)((unsigned long)q0 >> 32));
        float a1 = __frsqrt_rn(degf[r1] + 1.0f) * __uint_as_float((unsigned)((unsigned long)q1 >> 32));
        float a2 = __frsqrt_rn(degf[r2] + 1.0f) * __uint_as_float((unsigned)((unsigned long)q2 >> 32));
        float a3 = __frsqrt_rn(degf[r3] + 1.0f) * __uint_as_float((unsigned)((unsigned long)q3 >> 32));
        float a4 = __frsqrt_rn(degf[r4] + 1.0f) * __uint_as_float((unsigned)((unsigned long)q4 >> 32));
        float a5 = __frsqrt_rn(degf[r5] + 1.0f) * __uint_as_float((unsigned)((unsigned long)q5 >> 32));
        float a6 = __frsqrt_rn(degf[r6] + 1.0f) * __uint_as_float((unsigned)((unsigned long)q6 >> 32));
        float a7 = __frsqrt_rn(degf[r7] + 1.0f) * __uint_as_float((unsigned)((unsigned long)q7 >> 32));
        acc.x = fmaf(a0, bf_lo(u0), acc.x); acc.y = fmaf(a0, bf_hi(u0), acc.y);
        acc.x = fmaf(a1, bf_lo(u1), acc.x); acc.y = fmaf(a1, bf_hi(u1), acc.y);
        acc.x = fmaf(a2, bf_lo(u2), acc.x); acc.y = fmaf(a2, bf_hi(u2), acc.y);
        acc.x = fmaf(a3, bf_lo(u3), acc.x); acc.y = fmaf(a3, bf_hi(u3), acc.y);
        acc.x = fmaf(a4, bf_lo(u4), acc.x); acc.y = fmaf(a4, bf_hi(u4), acc.y);
        acc.x = fmaf(a5, bf_lo(u5), acc.x); acc.y = fmaf(a5, bf_hi(u5), acc.y);
        acc.x = fmaf(a6, bf_lo(u6), acc.x); acc.y = fmaf(a6, bf_hi(u6), acc.y);
        acc.x = fmaf(a7, bf_lo(u7), acc.x); acc.y = fmaf(a7, bf_hi(u7), acc.y);
        q0 = n0; q1 = n1; q2 = n2; q3 = n3; q4 = n4; q5 = n5; q6 = n6; q7 = n7;
    }
    for (; j < je; ++j) {
        long q = __builtin_nontemporal_load(spackl + j);
        int r = __builtin_amdgcn_readfirstlane((int)q);
        unsigned uu = hb[(size_t)r * 64 + lane];
        float a = __frsqrt_rn(degf[r] + 1.0f) * __uint_as_float((unsigned)((unsigned long)q >> 32));
        acc.x = fmaf(a, bf_lo(uu), acc.x);
        acc.y = fmaf(a, bf_hi(uu), acc.y);
    }

    int c0 = lane * 2;
    float2 bv = *(const float2*)(bias + c0);
    float2 o;
    o.x = bv.x + dn * acc.x;
    o.y = bv.y + dn * acc.y;
    union { float2 f; double d; } cvt;
    cvt.f = o;
    __builtin_nontemporal_store(cvt.d, (double*)(out + (size_t)node * 128 + c0));
}

extern "C" void kernel_launch(void* const* d_in, const int* in_sizes, int n_in,
                              void* d_out, int out_size, void* d_ws, size_t ws_size,
                              hipStream_t stream) {
    const float* x     = (const float*)d_in[0];
    const int*   eidx  = (const int*)d_in[1];   // [2,E] int32
    const float* eattr = (const float*)d_in[2];
    const float* W     = (const float*)d_in[3];
    const float* bias  = (const float*)d_in[4];
    int N = in_sizes[0] / 128;
    int E = in_sizes[2];
    const int* row = eidx;
    const int* col = eidx + E;

    char* p = (char*)d_ws;
    auto carve = [&](size_t bytes) {
        char* q = p;
        p += (bytes + 255) & ~(size_t)255;
        return q;
    };
    unsigned short* h   = (unsigned short*)carve((size_t)N * 128 * sizeof(unsigned short));
    unsigned short* Wtg = (unsigned short*)carve(128 * 128 * sizeof(unsigned short));
    char* zbase = carve((size_t)2 * N * sizeof(int));  // cnt + degf, zeroed together
    int*   cnt  = (int*)zbase;
    float* degf = (float*)(zbase + (size_t)N * sizeof(int));
    int*   rowptr = (int*)carve((size_t)(N + 1) * sizeof(int));
    int2*  spack  = (int2*)carve((size_t)E * sizeof(int2));
    int*   bsum   = (int*)carve(256 * sizeof(int));
    int*   boff   = (int*)carve(256 * sizeof(int));

    int NBLKD = (E + CHUNK_D - 1) / CHUNK_D;   // 391 deg blocks
    int NBLKP = (E + CHUNK_P - 1) / CHUNK_P;   // 782 place blocks
    int NBs = (N + ELEMS_PER_SCAN_BLOCK - 1) / ELEMS_PER_SCAN_BLOCK;  // 25
    int GB  = (N + 63) / 64;                   // 1563 gemm blocks

    hipMemsetAsync(zbase, 0, (size_t)2 * N * sizeof(int), stream);
    k_deg<<<NBLKD, 256, 0, stream>>>(col, W, cnt, Wtg, E);
    k_scan1<<<NBs, 256, 0, stream>>>(cnt, rowptr, bsum, N);
    k_scan2<<<1, 256, 0, stream>>>(bsum, boff, rowptr, N, E, NBs);
    k_pg<<<NBLKP + GB, 256, 0, stream>>>(row, col, eattr, rowptr, boff, cnt, degf,
                                         spack, x, Wtg, h, E, N, NBLKP);
    {
        size_t threads = (size_t)N * 64;
        int blocks = (int)((threads + 255) / 256);
        k_gather<<<blocks, 256, 0, stream>>>((const unsigned int*)h, degf, rowptr, boff,
                                             (const long*)spack, bias, (float*)d_out, N);
    }
}

// Round 8
// 248.477 us; speedup vs baseline: 1.6839x; 1.6839x over previous
//
#include <hip/hip_runtime.h>

// GCNConv: out = D^-1/2 (A+I) D^-1/2 X W + b
// N=100000, E=1600000, Din=Dout=128; x/W/b fp32, edge_index int32, out fp32.
//
// R12 = R11 resubmitted verbatim (bench infra failed; kernel re-audited:
// LDS sizes legal, scan race-free, K-split addressing aligned, fine sbuf
// 23-sigma headroom, no global atomics).
//  - GEMM K-split into two K=64 halves: LDS 52.2KB -> 27.6KB.
//  - place arrays sized to NCMAX=800: place LDS = 30.0KB.
//  - k_pg union = 30KB -> 5 blocks/CU (was 3); all gemm blocks fused there.
//  - k_fine standalone (25.7KB -> 6 blocks/CU).
//  - gather identical to R9 (74-75us; at random-256B service roofline).

#define ELEMS_PER_SCAN_BLOCK 4096  // 256 threads * 16
#define SCAN_SHIFT 12
#define CHUNK 2048                 // edges per hist/place block
#define NCMAX 800                  // >= NC = ceil(N/128) = 782

typedef __attribute__((ext_vector_type(8))) short short8;
typedef __attribute__((ext_vector_type(4))) float f32x4;

__device__ inline unsigned short f2bf(float f) {  // fp32 -> bf16 RNE
    unsigned u = __float_as_uint(f);
    u += 0x7fffu + ((u >> 16) & 1u);
    return (unsigned short)(u >> 16);
}
__device__ inline float bf_lo(unsigned u) { return __uint_as_float(u << 16); }
__device__ inline float bf_hi(unsigned u) { return __uint_as_float(u & 0xffff0000u); }

// ---- coarse histogram + W-prep fold ----
__global__ __launch_bounds__(256) void k_hist(const int* __restrict__ col,
                                              const float* __restrict__ W,
                                              int* __restrict__ histg,
                                              unsigned short* __restrict__ Wtg,
                                              int E, int NC, int NBLK) {
    __shared__ int lh[1024];
    int t = threadIdx.x, blk = blockIdx.x;
    if (blk < 64) {  // W transpose+bf16: 2 rows per block
        int n = blk * 2 + (t >> 7);
        int k = t & 127;
        Wtg[n * 128 + k] = f2bf(W[k * 128 + n]);
    }
    for (int i = t; i < 1024; i += 256) lh[i] = 0;
    __syncthreads();
    int base = blk * CHUNK;
    #pragma unroll
    for (int i = 0; i < CHUNK / 256; ++i) {
        int e = base + i * 256 + t;
        if (e < E) atomicAdd(&lh[col[e] >> 7], 1);
    }
    __syncthreads();
    for (int b = t; b < NC; b += 256) histg[b * NBLK + blk] = lh[b];
}

// ---- scan (2 kernels; block-offset applied by consumers) ----
__device__ inline int wave_incl_scan(int x, int lane) {
    #pragma unroll
    for (int d = 1; d < 64; d <<= 1) {
        int y = __shfl_up(x, d, 64);
        if (lane >= d) x += y;
    }
    return x;
}

__global__ void k_scan1(const int* __restrict__ in, int* __restrict__ out,
                        int* __restrict__ bsum, int M) {
    __shared__ int wsum[4];
    __shared__ int woff[4];
    int t = threadIdx.x, lane = t & 63, wid = t >> 6;
    int base = blockIdx.x * ELEMS_PER_SCAN_BLOCK + t * 16;
    int v[16];
    #pragma unroll
    for (int i = 0; i < 16; ++i) v[i] = (base + i < M) ? in[base + i] : 0;
    int run = 0;
    #pragma unroll
    for (int i = 0; i < 16; ++i) { int x = v[i]; v[i] = run; run += x; }
    int incl = wave_incl_scan(run, lane);
    int excl = incl - run;
    if (lane == 63) wsum[wid] = incl;
    __syncthreads();
    if (t == 0) {
        int r = 0;
        #pragma unroll
        for (int w = 0; w < 4; ++w) { int s = wsum[w]; woff[w] = r; r += s; }
        bsum[blockIdx.x] = r;
    }
    __syncthreads();
    int off = woff[wid] + excl;
    #pragma unroll
    for (int i = 0; i < 16; ++i)
        if (base + i < M) out[base + i] = v[i] + off;
}

__global__ void k_scan2(const int* __restrict__ bsum, int* __restrict__ boff, int NB) {
    __shared__ int wsum[4];
    __shared__ int woff[4];
    int t = threadIdx.x, lane = t & 63, wid = t >> 6;
    int x = (t < NB) ? bsum[t] : 0;
    int incl = wave_incl_scan(x, lane);
    int excl = incl - x;
    if (lane == 63) wsum[wid] = incl;
    __syncthreads();
    if (t == 0) {
        int r = 0;
        #pragma unroll
        for (int w = 0; w < 4; ++w) { int s = wsum[w]; woff[w] = r; r += s; }
    }
    __syncthreads();
    if (t < NB) boff[t] = woff[wid] + excl;
}

// ---- gemm smem (K-split halves): 27.6KB ----
struct GSmem { short Xs[64][72]; short Ws[128][72]; };  // 144B rows: 16B-aligned

__device__ __forceinline__ void gemm_body(GSmem& sm, const float* __restrict__ x,
                                          const unsigned short* __restrict__ Wtg,
                                          unsigned short* __restrict__ h,
                                          int row0, int N, int t) {
    int lane = t & 63, wid = t >> 6;
    int q = lane >> 4;
    int m = lane & 15;
    f32x4 acc[8];
    #pragma unroll
    for (int tde = 0; tde < 8; ++tde) acc[tde] = (f32x4){0.f, 0.f, 0.f, 0.f};

    #pragma unroll
    for (int kh = 0; kh < 2; ++kh) {
        {   // X half: 64 rows x 64 K; 16 floats/thread
            int r = t >> 2;
            int kf = (t & 3) * 16;
            int gr = row0 + r;
            const float4* src = (const float4*)(x + (size_t)gr * 128 + kh * 64 + kf);
            float4 a0 = make_float4(0.f, 0.f, 0.f, 0.f), a1 = a0, a2 = a0, a3 = a0;
            if (gr < N) { a0 = src[0]; a1 = src[1]; a2 = src[2]; a3 = src[3]; }
            short8 p0, p1;
            p0[0] = (short)f2bf(a0.x); p0[1] = (short)f2bf(a0.y);
            p0[2] = (short)f2bf(a0.z); p0[3] = (short)f2bf(a0.w);
            p0[4] = (short)f2bf(a1.x); p0[5] = (short)f2bf(a1.y);
            p0[6] = (short)f2bf(a1.z); p0[7] = (short)f2bf(a1.w);
            p1[0] = (short)f2bf(a2.x); p1[1] = (short)f2bf(a2.y);
            p1[2] = (short)f2bf(a2.z); p1[3] = (short)f2bf(a2.w);
            p1[4] = (short)f2bf(a3.x); p1[5] = (short)f2bf(a3.y);
            p1[6] = (short)f2bf(a3.z); p1[7] = (short)f2bf(a3.w);
            *(short8*)&sm.Xs[r][kf]     = p0;
            *(short8*)&sm.Xs[r][kf + 8] = p1;
        }
        {   // W half: 128 rows x 64 K; 32 shorts/thread
            int n = t >> 1;
            int off = (t & 1) * 32;
            const short* wsrc = (const short*)Wtg + n * 128 + kh * 64 + off;
            #pragma unroll
            for (int i = 0; i < 4; ++i)
                *(short8*)&sm.Ws[n][off + 8 * i] = *(const short8*)(wsrc + 8 * i);
        }
        __syncthreads();
        #pragma unroll
        for (int kc = 0; kc < 64; kc += 32) {
            short8 af = *(const short8*)&sm.Xs[wid * 16 + m][kc + q * 8];
            #pragma unroll
            for (int tde = 0; tde < 8; ++tde) {
                short8 bf = *(const short8*)&sm.Ws[tde * 16 + m][kc + q * 8];
                acc[tde] = __builtin_amdgcn_mfma_f32_16x16x32_bf16(af, bf, acc[tde], 0, 0, 0);
            }
        }
        __syncthreads();
    }
    #pragma unroll
    for (int r = 0; r < 4; ++r) {
        int grow = row0 + wid * 16 + q * 4 + r;
        if (grow < N) {
            #pragma unroll
            for (int tde = 0; tde < 8; ++tde)
                h[(size_t)grow * 128 + tde * 16 + m] = f2bf(acc[tde][r]);
        }
    }
}

// ---- fused: place (blocks [0,NBLK)) + ALL gemm (blocks [NBLK, NBLK+GB)) ----
__global__ __launch_bounds__(256) void k_pg(const int* __restrict__ row,
                                            const int* __restrict__ col,
                                            const float* __restrict__ wgt,
                                            const int* __restrict__ histg,
                                            const int* __restrict__ boff,
                                            int2* __restrict__ srw,
                                            const float* __restrict__ x,
                                            const unsigned short* __restrict__ Wtg,
                                            unsigned short* __restrict__ h,
                                            int E, int N, int NC, int NBLK) {
    __shared__ union {
        struct { int lcnt[NCMAX]; int gadj[NCMAX]; int2 stage[CHUNK]; int sdst[CHUNK];
                 int wsum[4]; int woff[4]; } p;   // 30.0 KB
        GSmem g;                                  // 27.6 KB
    } sm;
    int t = threadIdx.x;
    if ((int)blockIdx.x >= NBLK) {  // gemm branch
        gemm_body(sm.g, x, Wtg, h, ((int)blockIdx.x - NBLK) * 64, N, t);
        return;
    }
    int blk = blockIdx.x;
    int lane = t & 63, wid = t >> 6;
    int base = blk * CHUNK;
    int nE = min(CHUNK, E - base);
    for (int b = t; b < NCMAX; b += 256) sm.p.lcnt[b] = 0;
    __syncthreads();
    // pass A: local count
    #pragma unroll
    for (int i = 0; i < CHUNK / 256; ++i) {
        int e = base + i * 256 + t;
        if (e < E) atomicAdd(&sm.p.lcnt[col[e] >> 7], 1);
    }
    __syncthreads();
    // block-wide exclusive scan of lcnt[0..NCMAX), 4 entries/thread
    int c4[4];
    int sum = 0;
    #pragma unroll
    for (int i = 0; i < 4; ++i) {
        int idx = t * 4 + i;
        int v = (idx < NCMAX) ? sm.p.lcnt[idx] : 0;
        c4[i] = sum; sum += v;
    }
    int incl = wave_incl_scan(sum, lane);
    int excl = incl - sum;
    if (lane == 63) sm.p.wsum[wid] = incl;
    __syncthreads();
    if (t == 0) {
        int r = 0;
        #pragma unroll
        for (int w = 0; w < 4; ++w) { int s = sm.p.wsum[w]; sm.p.woff[w] = r; r += s; }
    }
    __syncthreads();
    int tb = sm.p.woff[wid] + excl;
    __syncthreads();
    #pragma unroll
    for (int i = 0; i < 4; ++i) {
        int idx = t * 4 + i;
        if (idx < NCMAX) {
            int b0 = tb + c4[i];
            int gb = 0;
            if (idx < NC) {
                int g = idx * NBLK + blk;
                gb = histg[g] + boff[g >> SCAN_SHIFT];  // scan3 folded
            }
            sm.p.gadj[idx] = gb - b0;
            sm.p.lcnt[idx] = b0;
        }
    }
    __syncthreads();
    // pass B: scatter into LDS by bucket
    #pragma unroll
    for (int i = 0; i < CHUNK / 256; ++i) {
        int e = base + i * 256 + t;
        if (e < E) {
            int c = col[e];
            int slot = atomicAdd(&sm.p.lcnt[c >> 7], 1);
            sm.p.stage[slot] = make_int2(((c & 127) << 17) | row[e], __float_as_int(wgt[e]));
            sm.p.sdst[slot] = sm.p.gadj[c >> 7] + slot;
        }
    }
    __syncthreads();
    for (int s_ = t; s_ < nE; s_ += 256) {
        srw[sm.p.sdst[s_]] = sm.p.stage[s_];
    }
}

// ---- fine: exact CSR within each 128-node bucket + dis + spack (standalone) ----
__global__ __launch_bounds__(256) void k_fine(const int* __restrict__ histg,
                                              const int* __restrict__ boff,
                                              const int2* __restrict__ srw,
                                              int* __restrict__ rowptr,
                                              float* __restrict__ dis,
                                              int2* __restrict__ spack,
                                              int E, int N, int NC, int NBLK) {
    __shared__ struct { int2 sbuf[3072]; int cnt128[128]; float degf[128];
                        int cur128[128]; int wtot[2]; } sf;   // 25.7 KB
    int t = threadIdx.x, b = blockIdx.x;
    int nb = b << 7;
    int g0 = b * NBLK;
    int start = histg[g0] + boff[g0 >> SCAN_SHIFT];
    int end;
    if (b == NC - 1) end = E;
    else {
        int g1 = (b + 1) * NBLK;
        end = histg[g1] + boff[g1 >> SCAN_SHIFT];
    }
    int cnt = end - start;
    int NL = min(cnt, 3072);
    if (t < 128) { sf.cnt128[t] = 0; sf.degf[t] = 1.0f; }  // 1.0 = self-loop
    __syncthreads();
    // phase 1: single global read; stage first NL entries into LDS
    for (int j = t; j < cnt; j += 256) {
        int2 s = srw[start + j];
        if (j < NL) sf.sbuf[j] = s;
        int c = s.x >> 17;
        atomicAdd(&sf.cnt128[c], 1);
        atomicAdd(&sf.degf[c], __int_as_float(s.y));
    }
    __syncthreads();
    // phase 2: 128-entry exclusive scan, write rowptr/dis, seed cursors
    int v = 0, incl = 0;
    if (t < 128) {
        v = sf.cnt128[t];
        incl = wave_incl_scan(v, t & 63);
        if ((t & 63) == 63) sf.wtot[t >> 6] = incl;
    }
    __syncthreads();
    if (t < 128) {
        int excl = incl - v + ((t >= 64) ? sf.wtot[0] : 0);
        int p = start + excl;
        sf.cur128[t] = p;
        int n = nb + t;
        if (n < N) {
            rowptr[n] = p;
            dis[n] = rsqrtf(sf.degf[t]);
        }
    }
    if (t == 0 && b == NC - 1) rowptr[N] = E;
    __syncthreads();
    // phase 3: final placement from LDS (global for rare overflow)
    for (int j = t; j < cnt; j += 256) {
        int2 s = (j < NL) ? sf.sbuf[j] : srw[start + j];
        int c = s.x >> 17;
        int pos = atomicAdd(&sf.cur128[c], 1);
        spack[pos] = make_int2(s.x & 0x1FFFF, s.y);
    }
}

// ---- gather: R9/R4 1-wave-per-node, unroll-8 + pipelined spack (unchanged) ----
__global__ __launch_bounds__(256) void k_gather(const unsigned int* __restrict__ hb,
                                                const float* __restrict__ dis,
                                                const int* __restrict__ rowptr,
                                                const long* __restrict__ spackl,
                                                const float* __restrict__ bias,
                                                float* __restrict__ out, int N) {
    int gid = blockIdx.x * blockDim.x + threadIdx.x;
    int node = gid >> 6;
    int lane = gid & 63;
    if (node >= N) return;
    node = __builtin_amdgcn_readfirstlane(node);

    float dn = dis[node];
    unsigned u = hb[(size_t)node * 64 + lane];
    float2 acc;
    acc.x = dn * bf_lo(u);
    acc.y = dn * bf_hi(u);

    int jb = rowptr[node], je = rowptr[node + 1];
    int j = jb;
    long q0, q1, q2, q3, q4, q5, q6, q7;
    if (j + 8 <= je) {
        q0 = __builtin_nontemporal_load(spackl + j);
        q1 = __builtin_nontemporal_load(spackl + j + 1);
        q2 = __builtin_nontemporal_load(spackl + j + 2);
        q3 = __builtin_nontemporal_load(spackl + j + 3);
        q4 = __builtin_nontemporal_load(spackl + j + 4);
        q5 = __builtin_nontemporal_load(spackl + j + 5);
        q6 = __builtin_nontemporal_load(spackl + j + 6);
        q7 = __builtin_nontemporal_load(spackl + j + 7);
    }
    for (; j + 8 <= je; j += 8) {
        int r0 = __builtin_amdgcn_readfirstlane((int)q0);
        int r1 = __builtin_amdgcn_readfirstlane((int)q1);
        int r2 = __builtin_amdgcn_readfirstlane((int)q2);
        int r3 = __builtin_amdgcn_readfirstlane((int)q3);
        int r4 = __builtin_amdgcn_readfirstlane((int)q4);
        int r5 = __builtin_amdgcn_readfirstlane((int)q5);
        int r6 = __builtin_amdgcn_readfirstlane((int)q6);
        int r7 = __builtin_amdgcn_readfirstlane((int)q7);
        unsigned u0 = hb[(size_t)r0 * 64 + lane];
        unsigned u1 = hb[(size_t)r1 * 64 + lane];
        unsigned u2 = hb[(size_t)r2 * 64 + lane];
        unsigned u3 = hb[(size_t)r3 * 64 + lane];
        unsigned u4 = hb[(size_t)r4 * 64 + lane];
        unsigned u5 = hb[(size_t)r5 * 64 + lane];
        unsigned u6 = hb[(size_t)r6 * 64 + lane];
        unsigned u7 = hb[(size_t)r7 * 64 + lane];
        int jn = (j + 16 <= je) ? j + 8 : j;
        long n0 = __builtin_nontemporal_load(spackl + jn);
        long n1 = __builtin_nontemporal_load(spackl + jn + 1);
        long n2 = __builtin_nontemporal_load(spackl + jn + 2);
        long n3 = __builtin_nontemporal_load(spackl + jn + 3);
        long n4 = __builtin_nontemporal_load(spackl + jn + 4);
        long n5 = __builtin_nontemporal_load(spackl + jn + 5);
        long n6 = __builtin_nontemporal_load(spackl + jn + 6);
        long n7 = __builtin_nontemporal_load(spackl + jn + 7);
        float a0 = dis[r0] * __uint_as_float((unsigned)((unsigned long)q0 >> 32));
        float a1 = dis[r1] * __uint_as_float((unsigned)((unsigned long)q1 >> 32));
        float a2 = dis[r2] * __uint_as_float((unsigned)((unsigned long)q2 >> 32));
        float a3 = dis[r3] * __uint_as_float((unsigned)((unsigned long)q3 >> 32));
        float a4 = dis[r4] * __uint_as_float((unsigned)((unsigned long)q4 >> 32));
        float a5 = dis[r5] * __uint_as_float((unsigned)((unsigned long)q5 >> 32));
        float a6 = dis[r6] * __uint_as_float((unsigned)((unsigned long)q6 >> 32));
        float a7 = dis[r7] * __uint_as_float((unsigned)((unsigned long)q7 >> 32));
        acc.x = fmaf(a0, bf_lo(u0), acc.x); acc.y = fmaf(a0, bf_hi(u0), acc.y);
        acc.x = fmaf(a1, bf_lo(u1), acc.x); acc.y = fmaf(a1, bf_hi(u1), acc.y);
        acc.x = fmaf(a2, bf_lo(u2), acc.x); acc.y = fmaf(a2, bf_hi(u2), acc.y);
        acc.x = fmaf(a3, bf_lo(u3), acc.x); acc.y = fmaf(a3, bf_hi(u3), acc.y);
        acc.x = fmaf(a4, bf_lo(u4), acc.x); acc.y = fmaf(a4, bf_hi(u4), acc.y);
        acc.x = fmaf(a5, bf_lo(u5), acc.x); acc.y = fmaf(a5, bf_hi(u5), acc.y);
        acc.x = fmaf(a6, bf_lo(u6), acc.x); acc.y = fmaf(a6, bf_hi(u6), acc.y);
        acc.x = fmaf(a7, bf_lo(u7), acc.x); acc.y = fmaf(a7, bf_hi(u7), acc.y);
        q0 = n0; q1 = n1; q2 = n2; q3 = n3; q4 = n4; q5 = n5; q6 = n6; q7 = n7;
    }
    for (; j < je; ++j) {
        long q = __builtin_nontemporal_load(spackl + j);
        int r = __builtin_amdgcn_readfirstlane((int)q);
        unsigned uu = hb[(size_t)r * 64 + lane];
        float a = dis[r] * __uint_as_float((unsigned)((unsigned long)q >> 32));
        acc.x = fmaf(a, bf_lo(uu), acc.x);
        acc.y = fmaf(a, bf_hi(uu), acc.y);
    }

    int c0 = lane * 2;
    float2 bv = *(const float2*)(bias + c0);
    float2 o;
    o.x = bv.x + dn * acc.x;
    o.y = bv.y + dn * acc.y;
    union { float2 f; double d; } cvt;
    cvt.f = o;
    __builtin_nontemporal_store(cvt.d, (double*)(out + (size_t)node * 128 + c0));
}

extern "C" void kernel_launch(void* const* d_in, const int* in_sizes, int n_in,
                              void* d_out, int out_size, void* d_ws, size_t ws_size,
                              hipStream_t stream) {
    const float* x     = (const float*)d_in[0];
    const int*   eidx  = (const int*)d_in[1];   // [2,E] int32
    const float* eattr = (const float*)d_in[2];
    const float* W     = (const float*)d_in[3];
    const float* bias  = (const float*)d_in[4];
    int N = in_sizes[0] / 128;
    int E = in_sizes[2];
    const int* row = eidx;
    const int* col = eidx + E;

    int NC = (N + 127) >> 7;                       // 782 coarse buckets
    int NBLK = (E + CHUNK - 1) / CHUNK;            // 782 hist/place blocks

    char* p = (char*)d_ws;
    auto carve = [&](size_t bytes) {
        char* q = p;
        p += (bytes + 255) & ~(size_t)255;
        return q;
    };
    unsigned short* h   = (unsigned short*)carve((size_t)N * 128 * sizeof(unsigned short));
    unsigned short* Wtg = (unsigned short*)carve(128 * 128 * sizeof(unsigned short));
    float* dis    = (float*)carve((size_t)N * sizeof(float));
    int*   rowptr = (int*)carve((size_t)(N + 1) * sizeof(int));
    int*   histg  = (int*)carve((size_t)NC * NBLK * sizeof(int));
    int2*  srw    = (int2*)carve((size_t)E * sizeof(int2));
    int2*  spack  = (int2*)carve((size_t)E * sizeof(int2));
    int*   bsum   = (int*)carve(256 * sizeof(int));
    int*   boff   = (int*)carve(256 * sizeof(int));

    int M = NC * NBLK;
    int NBs = (M + ELEMS_PER_SCAN_BLOCK - 1) / ELEMS_PER_SCAN_BLOCK;  // 150 <= 256
    int GB = (N + 63) / 64;   // 1563 gemm blocks

    k_hist<<<NBLK, 256, 0, stream>>>(col, W, histg, Wtg, E, NC, NBLK);
    k_scan1<<<NBs, 256, 0, stream>>>(histg, histg, bsum, M);
    k_scan2<<<1, 256, 0, stream>>>(bsum, boff, NBs);
    k_pg<<<NBLK + GB, 256, 0, stream>>>(row, col, eattr, histg, boff, srw,
                                        x, Wtg, h, E, N, NC, NBLK);
    k_fine<<<NC, 256, 0, stream>>>(histg, boff, srw, rowptr, dis, spack, E, N, NC, NBLK);
    {
        size_t threads = (size_t)N * 64;
        int blocks = (int)((threads + 255) / 256);
        k_gather<<<blocks, 256, 0, stream>>>((const unsigned int*)h, dis, rowptr,
                                             (const long*)spack, bias, (float*)d_out, N);
    }
}